// Round 9
// baseline (150.278 us; speedup 1.0000x reference)
//
#include <hip/hip_runtime.h>
#include <hip/hip_bf16.h>

#define DEV __device__ __forceinline__

typedef short bf16x8 __attribute__((ext_vector_type(8)));
typedef float f32x4  __attribute__((ext_vector_type(4)));
typedef float f32x16 __attribute__((ext_vector_type(16)));

#define Bc 2
#define Sc 2048
#define Dc 1024
#define Hc 16
// DEPTH = 64, M = B*S = 4096

// ---- workspace layout (bytes) ----
#define OFF_XB    0u           // batch bf16        [4096][1024]   8388608
#define OFF_WQKVT 8388608u     // Wqkv^T bf16       [3072][1024]   6291456
#define OFF_WOT   14680064u    // Wo^T bf16         [1024][1024]   2097152
#define OFF_Q     16777216u    // Q bf16 (B,H,S,64), pre-scaled    8388608
#define OFF_K     25165824u    // K bf16 (B,H,S,64)                8388608
#define OFF_VT    33554432u    // V^T bf16 (B,H,64,S)              8388608
#define OFF_XA    41943040u    // attn out bf16 [4096][1024]       8388608
#define OFF_BIASC 50331648u    // f32 [3072]                         12288
#define OFF_LENS  50343936u    // int [B]

DEV short f2bf(float f) {
    __hip_bfloat16 h = __float2bfloat16(f);
    union { __hip_bfloat16 h; short s; } u; u.h = h; return u.s;
}

DEV int cvtpk(float lo, float hi_) {
    int r;
    asm("v_cvt_pk_bf16_f32 %0, %1, %2" : "=v"(r) : "v"(lo), "v"(hi_));
    return r;
}

DEV void gload16(const void* g, void* l) {
    __builtin_amdgcn_global_load_lds((const __attribute__((address_space(1))) void*)g,
                                     (__attribute__((address_space(3))) void*)l, 16, 0, 0);
}

union I4BF { int i[4]; bf16x8 v; };

// V^T A-fragment with permuted k-slots (pairs with un-exchanged P fragment):
// slot (h, j<4) = key kkbyte/2 + 4h+j ; slot (h, j>=4) = key kkbyte/2 + 8+4h+(j-4)
DEV bf16x8 vread(const char* Vc, int row, int kkbyte, int hi8, int rsw) {
    union { short4 h[2]; bf16x8 v; } u;
    u.h[0] = *(const short4*)(Vc + row * 128 + ((kkbyte + hi8) ^ rsw));
    u.h[1] = *(const short4*)(Vc + row * 128 + ((kkbyte + 16 + hi8) ^ rsw));
    return u.v;
}

// ---------------- prep kernels ----------------

__global__ void cast_bf16_kernel(const float* __restrict__ in, short* __restrict__ out, int n4) {
    int i = blockIdx.x * blockDim.x + threadIdx.x;
    if (i >= n4) return;
    float4 v = ((const float4*)in)[i];
    short4 o;
    o.x = f2bf(v.x); o.y = f2bf(v.y); o.z = f2bf(v.z); o.w = f2bf(v.w);
    ((short4*)out)[i] = o;
}

// fused transpose-cast of the four 1024x1024 weight matrices (z selects matrix)
__global__ void wtrans_kernel(const float* __restrict__ Wq, const float* __restrict__ Wk,
                              const float* __restrict__ Wv, const float* __restrict__ Wo,
                              short* __restrict__ WQKVT, short* __restrict__ WOT) {
    const float* src; short* dst;
    int z = blockIdx.z;
    if (z == 0)      { src = Wq; dst = WQKVT; }
    else if (z == 1) { src = Wk; dst = WQKVT + 1024 * 1024; }
    else if (z == 2) { src = Wv; dst = WQKVT + 2 * 1024 * 1024; }
    else             { src = Wo; dst = WOT; }
    __shared__ float t[32][33];
    int tx = threadIdx.x, ty = threadIdx.y;               // 32 x 8
    int r0 = blockIdx.y * 32, c0 = blockIdx.x * 32;
#pragma unroll
    for (int i = 0; i < 4; i++)
        t[ty + i * 8][tx] = src[(size_t)(r0 + ty + i * 8) * Dc + c0 + tx];
    __syncthreads();
#pragma unroll
    for (int i = 0; i < 4; i++)
        dst[(size_t)(c0 + ty + i * 8) * Dc + r0 + tx] = f2bf(t[tx][ty + i * 8]);
}

// bias concat + mask lengths in one launch (block 0: bias; blocks 1,2: mask rows)
__global__ void prep_small_kernel(const float* __restrict__ bq, const float* __restrict__ bk,
                                  const float* __restrict__ bv,
                                  const unsigned char* __restrict__ mask,
                                  float* __restrict__ biasc, int* __restrict__ lens) {
    int blk = blockIdx.x, t = threadIdx.x;
    if (blk == 0) {
        if (t < Dc) { biasc[t] = bq[t]; biasc[Dc + t] = bk[t]; biasc[2 * Dc + t] = bv[t]; }
        return;
    }
    int b = blk - 1;
    bool is_i32 = (mask[1] == 0);
    __shared__ int cnt;
    if (t == 0) cnt = 0;
    __syncthreads();
    int local = 0;
    for (int s = t; s < Sc; s += blockDim.x) {
        bool v = is_i32 ? (((const int*)mask)[b * Sc + s] != 0) : (mask[b * Sc + s] != 0);
        local += v ? 1 : 0;
    }
    atomicAdd(&cnt, local);
    __syncthreads();
    if (t == 0) lens[b] = cnt;
}

// ---------------- 128x128 bf16 MFMA GEMM: QKV projection (V^T fused) ----------------
// bn<16: writes Q (scaled by 0.125*log2e) or K in (B,H,S,64).
// bn>=16: V block -> in-LDS transpose -> V^T (B,H,64,S) with coalesced 16B stores.
__global__ __launch_bounds__(256) void gemm_qkv_kernel(
    const short* __restrict__ A, const short* __restrict__ BT, const float* __restrict__ bias,
    short* __restrict__ Qp, short* __restrict__ Kp, short* __restrict__ VTp)
{
    __shared__ short As[128 * 32];
    __shared__ short Bs[128 * 32];
    __shared__ short Vt2[2][64][136];   // 2 heads x 64 d x (128 s + 8 pad)
    int tid = threadIdx.x, lane = tid & 63, wave = tid >> 6;
    int l15 = lane & 15, lhi = lane >> 4;
    int bm = blockIdx.x, bn = blockIdx.y;
    int wm = wave >> 1, wn = wave & 1;

    const f32x4 fzero = {0.f, 0.f, 0.f, 0.f};
    f32x4 acc[4][4];
#pragma unroll
    for (int i = 0; i < 4; i++)
#pragma unroll
        for (int j = 0; j < 4; j++) acc[i][j] = fzero;

    const char* Ab = (const char*)A;
    const char* Bb = (const char*)BT;

    for (int k0 = 0; k0 < 1024; k0 += 32) {
#pragma unroll
        for (int i = 0; i < 2; i++) {
            int o = wave * 2048 + i * 1024 + lane * 16;
            int row = o >> 6, cb = o & 63;
            gload16(Ab + ((size_t)(bm * 128 + row) * 1024 + k0) * 2 + cb,
                    (char*)As + wave * 2048 + i * 1024);
            gload16(Bb + ((size_t)(bn * 128 + row) * 1024 + k0) * 2 + cb,
                    (char*)Bs + wave * 2048 + i * 1024);
        }
        __syncthreads();
        bf16x8 af[4], bfv[4];
#pragma unroll
        for (int i = 0; i < 4; i++) {
            af[i]  = *(const bf16x8*)(As + (wm * 64 + i * 16 + l15) * 32 + lhi * 8);
            bfv[i] = *(const bf16x8*)(Bs + (wn * 64 + i * 16 + l15) * 32 + lhi * 8);
        }
#pragma unroll
        for (int i = 0; i < 4; i++)
#pragma unroll
            for (int j = 0; j < 4; j++)
                acc[i][j] = __builtin_amdgcn_mfma_f32_16x16x32_bf16(af[i], bfv[j], acc[i][j], 0, 0, 0);
        __syncthreads();
    }

    if (bn < 16) {
        // Q or K: direct global writes (row s, col d within head)
#pragma unroll
        for (int i = 0; i < 4; i++)
#pragma unroll
            for (int j = 0; j < 4; j++) {
                int c = bn * 128 + wn * 64 + j * 16 + l15;
                float bc = bias[c];
                int rb = bm * 128 + wm * 64 + i * 16 + 4 * lhi;
#pragma unroll
                for (int reg = 0; reg < 4; reg++) {
                    int r = rb + reg;
                    float v = acc[i][j][reg] + bc;
                    int which = c >> 10, cc = c & 1023, h = cc >> 6, d = cc & 63;
                    int b = r >> 11, s = r & 2047;
                    int bh = b * Hc + h;
                    if (which == 0) v *= 0.18033688f;   // fold 1/8 * log2(e) into Q
                    short sv = f2bf(v);
                    size_t idx = ((size_t)bh * Sc + s) * 64 + d;
                    if (which == 0) Qp[idx] = sv;
                    else            Kp[idx] = sv;
                }
            }
    } else {
        // V block: two heads (wn selects), transpose through LDS, write V^T coalesced
#pragma unroll
        for (int i = 0; i < 4; i++)
#pragma unroll
            for (int j = 0; j < 4; j++) {
                int c = bn * 128 + wn * 64 + j * 16 + l15;
                float bc = bias[c];
                int d = c & 63;
                int swb = wm * 64 + i * 16 + 4 * lhi;
                short4 pk;
                pk.x = f2bf(acc[i][j][0] + bc);
                pk.y = f2bf(acc[i][j][1] + bc);
                pk.z = f2bf(acc[i][j][2] + bc);
                pk.w = f2bf(acc[i][j][3] + bc);
                *(short4*)&Vt2[wn][d][swb] = pk;
            }
        __syncthreads();
        int u = tid;
        int tilei = u >> 7, rowd = (u >> 1) & 63, halfs = u & 1;
        int h = (bn - 16) * 2 + tilei;
        int b0 = bm >> 4, s0 = (bm & 15) * 128;
        short* orow = VTp + ((size_t)(b0 * Hc + h) * 64 + rowd) * Sc + s0 + halfs * 64;
        const short* lrow = &Vt2[tilei][rowd][halfs * 64];
#pragma unroll
        for (int k = 0; k < 8; k++)
            *(bf16x8*)(orow + k * 8) = *(const bf16x8*)(lrow + k * 8);
    }
}

// ---------------- 128x64 bf16 MFMA GEMM: output projection (f32 out) ----------------
__global__ __launch_bounds__(256) void gemm_out_kernel(
    const short* __restrict__ A, const short* __restrict__ BT, const float* __restrict__ bias,
    float* __restrict__ outF)
{
    __shared__ short As[128 * 32];
    __shared__ short Bs[64 * 32];
    int tid = threadIdx.x, lane = tid & 63, wave = tid >> 6;
    int l15 = lane & 15, lhi = lane >> 4;
    int bm = blockIdx.x, bn = blockIdx.y;

    const f32x4 fzero = {0.f, 0.f, 0.f, 0.f};
    f32x4 acc[2][4];
#pragma unroll
    for (int i = 0; i < 2; i++)
#pragma unroll
        for (int j = 0; j < 4; j++) acc[i][j] = fzero;

    const char* Ab = (const char*)A;
    const char* Bb = (const char*)BT;

    for (int k0 = 0; k0 < 1024; k0 += 32) {
#pragma unroll
        for (int i = 0; i < 2; i++) {
            int o = wave * 2048 + i * 1024 + lane * 16;
            int row = o >> 6, cb = o & 63;
            gload16(Ab + ((size_t)(bm * 128 + row) * 1024 + k0) * 2 + cb,
                    (char*)As + wave * 2048 + i * 1024);
        }
        {
            int o = wave * 1024 + lane * 16;
            int row = o >> 6, cb = o & 63;
            gload16(Bb + ((size_t)(bn * 64 + row) * 1024 + k0) * 2 + cb,
                    (char*)Bs + wave * 1024);
        }
        __syncthreads();
        bf16x8 af[2], bfv[4];
#pragma unroll
        for (int i = 0; i < 2; i++)
            af[i] = *(const bf16x8*)(As + (wave * 32 + i * 16 + l15) * 32 + lhi * 8);
#pragma unroll
        for (int j = 0; j < 4; j++)
            bfv[j] = *(const bf16x8*)(Bs + (j * 16 + l15) * 32 + lhi * 8);
#pragma unroll
        for (int i = 0; i < 2; i++)
#pragma unroll
            for (int j = 0; j < 4; j++)
                acc[i][j] = __builtin_amdgcn_mfma_f32_16x16x32_bf16(af[i], bfv[j], acc[i][j], 0, 0, 0);
        __syncthreads();
    }

#pragma unroll
    for (int i = 0; i < 2; i++)
#pragma unroll
        for (int j = 0; j < 4; j++) {
            int c = bn * 64 + j * 16 + l15;
            float bc = bias[c];
            int rb = bm * 128 + wave * 32 + i * 16 + 4 * lhi;
#pragma unroll
            for (int reg = 0; reg < 4; reg++)
                outF[(size_t)(rb + reg) * Dc + c] = acc[i][j][reg] + bc;
        }
}

// ---------------- flash attention: fixed-shift softmax, pi-permuted PV ----------------
// 1D grid 512, batch-BALANCED bijective XCD swizzle: XCD c owns heads {2c,2c+1} of BOTH
// batches (4 bh, 2MB K/V -> L2-resident) so per-XCD work = 16*2*(nt0+nt1), equal for all
// XCDs regardless of the per-batch valid lengths.
__global__ __launch_bounds__(256) void attn_kernel(
    const short* __restrict__ Qp, const short* __restrict__ Kp, const short* __restrict__ VTp,
    const int* __restrict__ lens, short* __restrict__ Xout)
{
    int tid = threadIdx.x, lane = tid & 63, wave = tid >> 6;
    int l31 = lane & 31, hi = lane >> 5;

    // physical XCD = orig & 7 (round-robin dispatch); idx enumerates the XCD's 64 blocks
    int orig = blockIdx.x;
    int xcd = orig & 7, idx = orig >> 3;
    int j = idx & 3, bx = idx >> 2;
    int bh = ((j >> 1) << 4) + xcd * 2 + (j & 1);   // bijective: {2c,2c+1,16+2c,17+2c}
    int b = bh >> 4, h = bh & 15;
    int q0 = bx * 128 + wave * 32;

    __shared__ short Kt[2][64 * 64];
    __shared__ short Vt[2][64 * 64];

    const short* Qb  = Qp + (size_t)bh * Sc * 64;
    const char*  Kb  = (const char*)(Kp + (size_t)bh * Sc * 64);
    const char*  VTb = (const char*)(VTp + (size_t)bh * 64 * Sc);

    bf16x8 qf[4];
#pragma unroll
    for (int kk = 0; kk < 4; kk++)
        qf[kk] = *(const bf16x8*)(Qb + (size_t)(q0 + l31) * 64 + kk * 16 + hi * 8);

    f32x16 xacc0, xacc1;
#pragma unroll
    for (int r = 0; r < 16; r++) { xacc0[r] = 0.f; xacc1[r] = 0.f; }
    float lreg = 0.f;

    int len = lens[b];
    int nt = (len + 63) >> 6;
    int rsw = (l31 & 7) << 4;
    int hi8 = hi * 8;

#define STAGE(bufi, kt_)                                                              \
    {                                                                                 \
        int k0_ = (kt_) * 64;                                                         \
        _Pragma("unroll")                                                             \
        for (int i = 0; i < 2; i++) {                                                 \
            int o = wave * 2048 + i * 1024 + lane * 16;                               \
            int row = o >> 7, cb = o & 127;                                           \
            int scb = cb ^ ((row & 7) << 4);                                          \
            gload16(Kb + (size_t)(k0_ + row) * 128 + scb,                             \
                    (char*)&Kt[bufi][0] + wave * 2048 + i * 1024);                    \
            gload16(VTb + (size_t)row * (Sc * 2) + (size_t)k0_ * 2 + scb,             \
                    (char*)&Vt[bufi][0] + wave * 2048 + i * 1024);                    \
        }                                                                             \
    }

#define DOHALF(Kc, Vc, ROFF, KBASE, KT)                                               \
    {                                                                                 \
        f32x16 s;                                                                     \
        _Pragma("unroll")                                                             \
        for (int r = 0; r < 16; r++) s[r] = 0.f;                                      \
        __builtin_amdgcn_s_setprio(1);                                                \
        _Pragma("unroll")                                                             \
        for (int kk = 0; kk < 4; kk++) {                                              \
            bf16x8 kf = *(const bf16x8*)((Kc) + (ROFF + l31) * 128 +                  \
                                         ((kk * 32 + hi * 16) ^ rsw));                \
            s = __builtin_amdgcn_mfma_f32_32x32x16_bf16(kf, qf[kk], s, 0, 0, 0);      \
        }                                                                             \
        __builtin_amdgcn_s_setprio(0);                                                \
        if ((KT) == nt - 1) {                                                         \
            int rem = len - (KT) * 64;                                                \
            if (rem < (KBASE) + 32) {                                                 \
                _Pragma("unroll")                                                     \
                for (int r = 0; r < 16; r++) {                                        \
                    int key0 = (KBASE) + 4 * hi + (r & 3) + 8 * (r >> 2);             \
                    if (key0 >= rem) s[r] = -3.0e38f;                                 \
                }                                                                     \
            }                                                                         \
        }                                                                             \
        _Pragma("unroll")                                                             \
        for (int r = 0; r < 16; r++) { s[r] = exp2f(s[r]); lreg += s[r]; }            \
        I4BF u, w;                                                                    \
        u.i[0] = cvtpk(s[0], s[1]);   u.i[1] = cvtpk(s[2], s[3]);                     \
        u.i[2] = cvtpk(s[4], s[5]);   u.i[3] = cvtpk(s[6], s[7]);                     \
        w.i[0] = cvtpk(s[8], s[9]);   w.i[1] = cvtpk(s[10], s[11]);                   \
        w.i[2] = cvtpk(s[12], s[13]); w.i[3] = cvtpk(s[14], s[15]);                   \
        __builtin_amdgcn_s_setprio(1);                                                \
        {                                                                             \
            bf16x8 v0 = vread((Vc), l31,      (KBASE) * 2,      hi8, rsw);            \
            bf16x8 v1 = vread((Vc), 32 + l31, (KBASE) * 2,      hi8, rsw);            \
            xacc0 = __builtin_amdgcn_mfma_f32_32x32x16_bf16(v0, u.v, xacc0, 0, 0, 0); \
            xacc1 = __builtin_amdgcn_mfma_f32_32x32x16_bf16(v1, u.v, xacc1, 0, 0, 0); \
            bf16x8 v2 = vread((Vc), l31,      (KBASE) * 2 + 32, hi8, rsw);            \
            bf16x8 v3 = vread((Vc), 32 + l31, (KBASE) * 2 + 32, hi8, rsw);            \
            xacc0 = __builtin_amdgcn_mfma_f32_32x32x16_bf16(v2, w.v, xacc0, 0, 0, 0); \
            xacc1 = __builtin_amdgcn_mfma_f32_32x32x16_bf16(v3, w.v, xacc1, 0, 0, 0); \
        }                                                                             \
        __builtin_amdgcn_s_setprio(0);                                                \
    }

#define DOTILE(BUFI, KT)                                                              \
    {                                                                                 \
        const char* Kc_ = (const char*)&Kt[BUFI][0];                                  \
        const char* Vc_ = (const char*)&Vt[BUFI][0];                                  \
        DOHALF(Kc_, Vc_, 0, 0, KT);                                                   \
        DOHALF(Kc_, Vc_, 32, 32, KT);                                                 \
    }

    STAGE(0, 0);
    __syncthreads();

    int kt = 0;
    while (kt + 2 <= nt) {
        if (kt + 1 < nt) STAGE(1, kt + 1);
        DOTILE(0, kt);
        __syncthreads();
        if (kt + 2 < nt) STAGE(0, kt + 2);
        DOTILE(1, kt + 1);
        __syncthreads();
        kt += 2;
    }
    if (kt < nt) DOTILE(0, kt);

    // epilogue: l = sum over both lane halves; d = {0,32} + 4*hi + 8*g + (0..3)
    float lfull = lreg + __shfl_xor(lreg, 32, 64);
    float rl = 1.0f / lfull;
    short* orow = Xout + (size_t)(b * Sc + q0 + l31) * Dc + h * 64;
#pragma unroll
    for (int g = 0; g < 4; g++) {
        short4 o;
        o.x = f2bf(xacc0[4 * g + 0] * rl);
        o.y = f2bf(xacc0[4 * g + 1] * rl);
        o.z = f2bf(xacc0[4 * g + 2] * rl);
        o.w = f2bf(xacc0[4 * g + 3] * rl);
        *(short4*)(orow + 4 * hi + 8 * g) = o;
    }
#pragma unroll
    for (int g = 0; g < 4; g++) {
        short4 o;
        o.x = f2bf(xacc1[4 * g + 0] * rl);
        o.y = f2bf(xacc1[4 * g + 1] * rl);
        o.z = f2bf(xacc1[4 * g + 2] * rl);
        o.w = f2bf(xacc1[4 * g + 3] * rl);
        *(short4*)(orow + 32 + 4 * hi + 8 * g) = o;
    }
}

// ---------------- launch ----------------

extern "C" void kernel_launch(void* const* d_in, const int* in_sizes, int n_in,
                              void* d_out, int out_size, void* d_ws, size_t ws_size,
                              hipStream_t stream) {
    const float* batch = (const float*)d_in[0];
    const unsigned char* mask = (const unsigned char*)d_in[1];
    const float* Wq = (const float*)d_in[2];
    const float* bq = (const float*)d_in[3];
    const float* Wk = (const float*)d_in[4];
    const float* bk = (const float*)d_in[5];
    const float* Wv = (const float*)d_in[6];
    const float* bv = (const float*)d_in[7];
    const float* Wo = (const float*)d_in[8];
    const float* bo = (const float*)d_in[9];

    char* ws = (char*)d_ws;
    short* XB    = (short*)(ws + OFF_XB);
    short* WQKVT = (short*)(ws + OFF_WQKVT);
    short* WOT   = (short*)(ws + OFF_WOT);
    short* Qb    = (short*)(ws + OFF_Q);
    short* Kb    = (short*)(ws + OFF_K);
    short* VTb   = (short*)(ws + OFF_VT);
    short* XAb   = (short*)(ws + OFF_XA);
    float* BIASC = (float*)(ws + OFF_BIASC);
    int*   LENS  = (int*)(ws + OFF_LENS);

    cast_bf16_kernel<<<4096, 256, 0, stream>>>(batch, XB, 1048576);
    wtrans_kernel<<<dim3(32, 32, 4), dim3(32, 8), 0, stream>>>(Wq, Wk, Wv, Wo, WQKVT, WOT);
    prep_small_kernel<<<3, 1024, 0, stream>>>(bq, bk, bv, mask, BIASC, LENS);

    gemm_qkv_kernel<<<dim3(32, 24), 256, 0, stream>>>(XB, WQKVT, BIASC, Qb, Kb, VTb);
    attn_kernel<<<512, 256, 0, stream>>>(Qb, Kb, VTb, LENS, XAb);
    gemm_out_kernel<<<dim3(32, 16), 256, 0, stream>>>(XAb, WOT, bo, (float*)d_out);
}

// Round 10
// 124.659 us; speedup vs baseline: 1.2055x; 1.2055x over previous
//
#include <hip/hip_runtime.h>
#include <hip/hip_bf16.h>

#define DEV __device__ __forceinline__

typedef short bf16x8 __attribute__((ext_vector_type(8)));
typedef float f32x4  __attribute__((ext_vector_type(4)));
typedef float f32x16 __attribute__((ext_vector_type(16)));

#define Bc 2
#define Sc 2048
#define Dc 1024
#define Hc 16
// DEPTH = 64, M = B*S = 4096

// ---- workspace layout (bytes) ----
#define OFF_XB    0u           // batch bf16        [4096][1024]   8388608
#define OFF_WQKVT 8388608u     // Wqkv^T bf16       [3072][1024]   6291456
#define OFF_WOT   14680064u    // Wo^T bf16         [1024][1024]   2097152
#define OFF_Q     16777216u    // Q bf16 (B,H,S,64), pre-scaled    8388608
#define OFF_K     25165824u    // K bf16 (B,H,S,64)                8388608
#define OFF_VT    33554432u    // V^T bf16 (B,H,64,S)              8388608
#define OFF_XA    41943040u    // attn out bf16 [4096][1024]       8388608
#define OFF_BIASC 50331648u    // f32 [3072]                         12288
#define OFF_LENS  50343936u    // int [B]
// V (B,H,S,64) bf16 scratch lives in d_out[0..8MB) — rewritten every call,
// consumed by vtrans, then fully overwritten by gemm_out (deterministic).

DEV short f2bf(float f) {
    __hip_bfloat16 h = __float2bfloat16(f);
    union { __hip_bfloat16 h; short s; } u; u.h = h; return u.s;
}

DEV int cvtpk(float lo, float hi_) {
    int r;
    asm("v_cvt_pk_bf16_f32 %0, %1, %2" : "=v"(r) : "v"(lo), "v"(hi_));
    return r;
}

DEV float vexp2(float x) {
    float r;
    asm("v_exp_f32 %0, %1" : "=v"(r) : "v"(x));   // hardware 2^x, ~1 ULP
    return r;
}

DEV void gload16(const void* g, void* l) {
    __builtin_amdgcn_global_load_lds((const __attribute__((address_space(1))) void*)g,
                                     (__attribute__((address_space(3))) void*)l, 16, 0, 0);
}

union I4BF { int i[4]; bf16x8 v; };

// V^T A-fragment with permuted k-slots (pairs with un-exchanged P fragment):
// slot (h, j<4) = key kkbyte/2 + 4h+j ; slot (h, j>=4) = key kkbyte/2 + 8+4h+(j-4)
DEV bf16x8 vread(const char* Vc, int row, int kkbyte, int hi8, int rsw) {
    union { short4 h[2]; bf16x8 v; } u;
    u.h[0] = *(const short4*)(Vc + row * 128 + ((kkbyte + hi8) ^ rsw));
    u.h[1] = *(const short4*)(Vc + row * 128 + ((kkbyte + 16 + hi8) ^ rsw));
    return u.v;
}

// ---------------- prep kernels ----------------

__global__ void cast_bf16_kernel(const float* __restrict__ in, short* __restrict__ out, int n4) {
    int i = blockIdx.x * blockDim.x + threadIdx.x;
    if (i >= n4) return;
    float4 v = ((const float4*)in)[i];
    short4 o;
    o.x = f2bf(v.x); o.y = f2bf(v.y); o.z = f2bf(v.z); o.w = f2bf(v.w);
    ((short4*)out)[i] = o;
}

// fused transpose-cast of the four 1024x1024 weight matrices (z selects matrix)
__global__ void wtrans_kernel(const float* __restrict__ Wq, const float* __restrict__ Wk,
                              const float* __restrict__ Wv, const float* __restrict__ Wo,
                              short* __restrict__ WQKVT, short* __restrict__ WOT) {
    const float* src; short* dst;
    int z = blockIdx.z;
    if (z == 0)      { src = Wq; dst = WQKVT; }
    else if (z == 1) { src = Wk; dst = WQKVT + 1024 * 1024; }
    else if (z == 2) { src = Wv; dst = WQKVT + 2 * 1024 * 1024; }
    else             { src = Wo; dst = WOT; }
    __shared__ float t[32][33];
    int tx = threadIdx.x, ty = threadIdx.y;               // 32 x 8
    int r0 = blockIdx.y * 32, c0 = blockIdx.x * 32;
#pragma unroll
    for (int i = 0; i < 4; i++)
        t[ty + i * 8][tx] = src[(size_t)(r0 + ty + i * 8) * Dc + c0 + tx];
    __syncthreads();
#pragma unroll
    for (int i = 0; i < 4; i++)
        dst[(size_t)(c0 + ty + i * 8) * Dc + r0 + tx] = f2bf(t[tx][ty + i * 8]);
}

// bias concat + mask lengths in one launch (block 0: bias; blocks 1,2: mask rows)
__global__ void prep_small_kernel(const float* __restrict__ bq, const float* __restrict__ bk,
                                  const float* __restrict__ bv,
                                  const unsigned char* __restrict__ mask,
                                  float* __restrict__ biasc, int* __restrict__ lens) {
    int blk = blockIdx.x, t = threadIdx.x;
    if (blk == 0) {
        if (t < Dc) { biasc[t] = bq[t]; biasc[Dc + t] = bk[t]; biasc[2 * Dc + t] = bv[t]; }
        return;
    }
    int b = blk - 1;
    bool is_i32 = (mask[1] == 0);
    __shared__ int cnt;
    if (t == 0) cnt = 0;
    __syncthreads();
    int local = 0;
    for (int s = t; s < Sc; s += blockDim.x) {
        bool v = is_i32 ? (((const int*)mask)[b * Sc + s] != 0) : (mask[b * Sc + s] != 0);
        local += v ? 1 : 0;
    }
    atomicAdd(&cnt, local);
    __syncthreads();
    if (t == 0) lens[b] = cnt;
}

// V (B,H,S,64) -> V^T (B,H,64,S), LDS-tiled, coalesced both sides
__global__ __launch_bounds__(256) void vtrans_kernel(const short* __restrict__ V,
                                                     short* __restrict__ VT) {
    __shared__ short t[64][65];
    int tid = threadIdx.x;
    int bh = blockIdx.y, s0 = blockIdx.x * 64;
    int rr = tid >> 2, c4 = (tid & 3) * 16;
    const short* vrow = V + ((size_t)bh * Sc + s0 + rr) * 64 + c4;
    *(bf16x8*)&t[rr][c4]     = *(const bf16x8*)(vrow);
    *(bf16x8*)&t[rr][c4 + 8] = *(const bf16x8*)(vrow + 8);
    __syncthreads();
    bf16x8 a, b2;
#pragma unroll
    for (int i = 0; i < 8; i++) { a[i] = t[c4 + i][rr]; b2[i] = t[c4 + 8 + i][rr]; }
    short* orow = VT + ((size_t)bh * 64 + rr) * Sc + s0 + c4;
    *(bf16x8*)(orow)     = a;
    *(bf16x8*)(orow + 8) = b2;
}

// ---------------- 128x128 bf16 MFMA GEMM: QKV projection ----------------
__global__ __launch_bounds__(256) void gemm_qkv_kernel(
    const short* __restrict__ A, const short* __restrict__ BT, const float* __restrict__ bias,
    short* __restrict__ Qp, short* __restrict__ Kp, short* __restrict__ Vp)
{
    __shared__ short As[128 * 32];
    __shared__ short Bs[128 * 32];
    int tid = threadIdx.x, lane = tid & 63, wave = tid >> 6;
    int l15 = lane & 15, lhi = lane >> 4;
    int bm = blockIdx.x, bn = blockIdx.y;
    int wm = wave >> 1, wn = wave & 1;

    const f32x4 fzero = {0.f, 0.f, 0.f, 0.f};
    f32x4 acc[4][4];
#pragma unroll
    for (int i = 0; i < 4; i++)
#pragma unroll
        for (int j = 0; j < 4; j++) acc[i][j] = fzero;

    const char* Ab = (const char*)A;
    const char* Bb = (const char*)BT;

    for (int k0 = 0; k0 < 1024; k0 += 32) {
#pragma unroll
        for (int i = 0; i < 2; i++) {
            int o = wave * 2048 + i * 1024 + lane * 16;
            int row = o >> 6, cb = o & 63;
            gload16(Ab + ((size_t)(bm * 128 + row) * 1024 + k0) * 2 + cb,
                    (char*)As + wave * 2048 + i * 1024);
            gload16(Bb + ((size_t)(bn * 128 + row) * 1024 + k0) * 2 + cb,
                    (char*)Bs + wave * 2048 + i * 1024);
        }
        __syncthreads();
        bf16x8 af[4], bfv[4];
#pragma unroll
        for (int i = 0; i < 4; i++) {
            af[i]  = *(const bf16x8*)(As + (wm * 64 + i * 16 + l15) * 32 + lhi * 8);
            bfv[i] = *(const bf16x8*)(Bs + (wn * 64 + i * 16 + l15) * 32 + lhi * 8);
        }
#pragma unroll
        for (int i = 0; i < 4; i++)
#pragma unroll
            for (int j = 0; j < 4; j++)
                acc[i][j] = __builtin_amdgcn_mfma_f32_16x16x32_bf16(af[i], bfv[j], acc[i][j], 0, 0, 0);
        __syncthreads();
    }

#pragma unroll
    for (int i = 0; i < 4; i++)
#pragma unroll
        for (int j = 0; j < 4; j++) {
            int c = bn * 128 + wn * 64 + j * 16 + l15;
            float bc = bias[c];
            int rb = bm * 128 + wm * 64 + i * 16 + 4 * lhi;
#pragma unroll
            for (int reg = 0; reg < 4; reg++) {
                int r = rb + reg;
                float v = acc[i][j][reg] + bc;
                int which = c >> 10, cc = c & 1023, h = cc >> 6, d = cc & 63;
                int b = r >> 11, s = r & 2047;
                int bh = b * Hc + h;
                if (which == 0) v *= 0.18033688f;   // fold 1/8 * log2(e) into Q
                short sv = f2bf(v);
                size_t idx = ((size_t)bh * Sc + s) * 64 + d;
                if (which == 0)      Qp[idx] = sv;
                else if (which == 1) Kp[idx] = sv;
                else                 Vp[idx] = sv;
            }
        }
}

// ---------------- 128x64 bf16 MFMA GEMM: output projection (f32 out) ----------------
__global__ __launch_bounds__(256) void gemm_out_kernel(
    const short* __restrict__ A, const short* __restrict__ BT, const float* __restrict__ bias,
    float* __restrict__ outF)
{
    __shared__ short As[128 * 32];
    __shared__ short Bs[64 * 32];
    int tid = threadIdx.x, lane = tid & 63, wave = tid >> 6;
    int l15 = lane & 15, lhi = lane >> 4;
    int bm = blockIdx.x, bn = blockIdx.y;

    const f32x4 fzero = {0.f, 0.f, 0.f, 0.f};
    f32x4 acc[2][4];
#pragma unroll
    for (int i = 0; i < 2; i++)
#pragma unroll
        for (int j = 0; j < 4; j++) acc[i][j] = fzero;

    const char* Ab = (const char*)A;
    const char* Bb = (const char*)BT;

    for (int k0 = 0; k0 < 1024; k0 += 32) {
#pragma unroll
        for (int i = 0; i < 2; i++) {
            int o = wave * 2048 + i * 1024 + lane * 16;
            int row = o >> 6, cb = o & 63;
            gload16(Ab + ((size_t)(bm * 128 + row) * 1024 + k0) * 2 + cb,
                    (char*)As + wave * 2048 + i * 1024);
        }
        {
            int o = wave * 1024 + lane * 16;
            int row = o >> 6, cb = o & 63;
            gload16(Bb + ((size_t)(bn * 64 + row) * 1024 + k0) * 2 + cb,
                    (char*)Bs + wave * 1024);
        }
        __syncthreads();
        bf16x8 af[2], bfv[4];
#pragma unroll
        for (int i = 0; i < 2; i++)
            af[i] = *(const bf16x8*)(As + (wave * 32 + i * 16 + l15) * 32 + lhi * 8);
#pragma unroll
        for (int j = 0; j < 4; j++)
            bfv[j] = *(const bf16x8*)(Bs + (j * 16 + l15) * 32 + lhi * 8);
#pragma unroll
        for (int i = 0; i < 2; i++)
#pragma unroll
            for (int j = 0; j < 4; j++)
                acc[i][j] = __builtin_amdgcn_mfma_f32_16x16x32_bf16(af[i], bfv[j], acc[i][j], 0, 0, 0);
        __syncthreads();
    }

#pragma unroll
    for (int i = 0; i < 2; i++)
#pragma unroll
        for (int j = 0; j < 4; j++) {
            int c = bn * 64 + j * 16 + l15;
            float bc = bias[c];
            int rb = bm * 128 + wave * 32 + i * 16 + 4 * lhi;
#pragma unroll
            for (int reg = 0; reg < 4; reg++)
                outF[(size_t)(rb + reg) * Dc + c] = acc[i][j][reg] + bc;
        }
}

// ---------------- flash attention: fixed-shift softmax, pi-permuted PV ----------------
// 1D grid 512, batch-BALANCED bijective XCD swizzle (XCD c owns heads {2c,2c+1} of both
// batches -> equal tile counts per XCD, 2MB K/V L2-resident). Raw v_exp_f32; tree-sum l.
__global__ __launch_bounds__(256) void attn_kernel(
    const short* __restrict__ Qp, const short* __restrict__ Kp, const short* __restrict__ VTp,
    const int* __restrict__ lens, short* __restrict__ Xout)
{
    int tid = threadIdx.x, lane = tid & 63, wave = tid >> 6;
    int l31 = lane & 31, hi = lane >> 5;

    int orig = blockIdx.x;
    int xcd = orig & 7, idx = orig >> 3;
    int j = idx & 3, bx = idx >> 2;
    int bh = ((j >> 1) << 4) + xcd * 2 + (j & 1);   // bijective: {2c,2c+1,16+2c,17+2c}
    int b = bh >> 4, h = bh & 15;
    int q0 = bx * 128 + wave * 32;

    __shared__ short Kt[2][64 * 64];
    __shared__ short Vt[2][64 * 64];

    const short* Qb  = Qp + (size_t)bh * Sc * 64;
    const char*  Kb  = (const char*)(Kp + (size_t)bh * Sc * 64);
    const char*  VTb = (const char*)(VTp + (size_t)bh * 64 * Sc);

    bf16x8 qf[4];
#pragma unroll
    for (int kk = 0; kk < 4; kk++)
        qf[kk] = *(const bf16x8*)(Qb + (size_t)(q0 + l31) * 64 + kk * 16 + hi * 8);

    f32x16 xacc0, xacc1;
#pragma unroll
    for (int r = 0; r < 16; r++) { xacc0[r] = 0.f; xacc1[r] = 0.f; }
    float lreg = 0.f;

    int len = lens[b];
    int nt = (len + 63) >> 6;
    int rsw = (l31 & 7) << 4;
    int hi8 = hi * 8;

#define STAGE(bufi, kt_)                                                              \
    {                                                                                 \
        int k0_ = (kt_) * 64;                                                         \
        _Pragma("unroll")                                                             \
        for (int i = 0; i < 2; i++) {                                                 \
            int o = wave * 2048 + i * 1024 + lane * 16;                               \
            int row = o >> 7, cb = o & 127;                                           \
            int scb = cb ^ ((row & 7) << 4);                                          \
            gload16(Kb + (size_t)(k0_ + row) * 128 + scb,                             \
                    (char*)&Kt[bufi][0] + wave * 2048 + i * 1024);                    \
            gload16(VTb + (size_t)row * (Sc * 2) + (size_t)k0_ * 2 + scb,             \
                    (char*)&Vt[bufi][0] + wave * 2048 + i * 1024);                    \
        }                                                                             \
    }

#define DOHALF(Kc, Vc, ROFF, KBASE, KT)                                               \
    {                                                                                 \
        f32x16 s;                                                                     \
        _Pragma("unroll")                                                             \
        for (int r = 0; r < 16; r++) s[r] = 0.f;                                      \
        __builtin_amdgcn_s_setprio(1);                                                \
        _Pragma("unroll")                                                             \
        for (int kk = 0; kk < 4; kk++) {                                              \
            bf16x8 kf = *(const bf16x8*)((Kc) + (ROFF + l31) * 128 +                  \
                                         ((kk * 32 + hi * 16) ^ rsw));                \
            s = __builtin_amdgcn_mfma_f32_32x32x16_bf16(kf, qf[kk], s, 0, 0, 0);      \
        }                                                                             \
        __builtin_amdgcn_s_setprio(0);                                                \
        if ((KT) == nt - 1) {                                                         \
            int rem = len - (KT) * 64;                                                \
            if (rem < (KBASE) + 32) {                                                 \
                _Pragma("unroll")                                                     \
                for (int r = 0; r < 16; r++) {                                        \
                    int key0 = (KBASE) + 4 * hi + (r & 3) + 8 * (r >> 2);             \
                    if (key0 >= rem) s[r] = -3.0e38f;                                 \
                }                                                                     \
            }                                                                         \
        }                                                                             \
        _Pragma("unroll")                                                             \
        for (int r = 0; r < 16; r++) s[r] = vexp2(s[r]);                              \
        {   /* depth-4 tree sum (breaks the 16-deep serial add chain) */              \
            float a0 = s[0] + s[1],   a1 = s[2] + s[3];                               \
            float a2 = s[4] + s[5],   a3 = s[6] + s[7];                               \
            float a4 = s[8] + s[9],   a5 = s[10] + s[11];                             \
            float a6 = s[12] + s[13], a7 = s[14] + s[15];                             \
            float b0 = a0 + a1, b1 = a2 + a3, b2 = a4 + a5, b3 = a6 + a7;             \
            lreg += (b0 + b1) + (b2 + b3);                                            \
        }                                                                             \
        I4BF u, w;                                                                    \
        u.i[0] = cvtpk(s[0], s[1]);   u.i[1] = cvtpk(s[2], s[3]);                     \
        u.i[2] = cvtpk(s[4], s[5]);   u.i[3] = cvtpk(s[6], s[7]);                     \
        w.i[0] = cvtpk(s[8], s[9]);   w.i[1] = cvtpk(s[10], s[11]);                   \
        w.i[2] = cvtpk(s[12], s[13]); w.i[3] = cvtpk(s[14], s[15]);                   \
        __builtin_amdgcn_s_setprio(1);                                                \
        {                                                                             \
            bf16x8 v0 = vread((Vc), l31,      (KBASE) * 2,      hi8, rsw);            \
            bf16x8 v1 = vread((Vc), 32 + l31, (KBASE) * 2,      hi8, rsw);            \
            xacc0 = __builtin_amdgcn_mfma_f32_32x32x16_bf16(v0, u.v, xacc0, 0, 0, 0); \
            xacc1 = __builtin_amdgcn_mfma_f32_32x32x16_bf16(v1, u.v, xacc1, 0, 0, 0); \
            bf16x8 v2 = vread((Vc), l31,      (KBASE) * 2 + 32, hi8, rsw);            \
            bf16x8 v3 = vread((Vc), 32 + l31, (KBASE) * 2 + 32, hi8, rsw);            \
            xacc0 = __builtin_amdgcn_mfma_f32_32x32x16_bf16(v2, w.v, xacc0, 0, 0, 0); \
            xacc1 = __builtin_amdgcn_mfma_f32_32x32x16_bf16(v3, w.v, xacc1, 0, 0, 0); \
        }                                                                             \
        __builtin_amdgcn_s_setprio(0);                                                \
    }

#define DOTILE(BUFI, KT)                                                              \
    {                                                                                 \
        const char* Kc_ = (const char*)&Kt[BUFI][0];                                  \
        const char* Vc_ = (const char*)&Vt[BUFI][0];                                  \
        DOHALF(Kc_, Vc_, 0, 0, KT);                                                   \
        DOHALF(Kc_, Vc_, 32, 32, KT);                                                 \
    }

    STAGE(0, 0);
    __syncthreads();

    int kt = 0;
    while (kt + 2 <= nt) {
        if (kt + 1 < nt) STAGE(1, kt + 1);
        DOTILE(0, kt);
        __syncthreads();
        if (kt + 2 < nt) STAGE(0, kt + 2);
        DOTILE(1, kt + 1);
        __syncthreads();
        kt += 2;
    }
    if (kt < nt) DOTILE(0, kt);

    // epilogue: l = sum over both lane halves; d = {0,32} + 4*hi + 8*g + (0..3)
    float lfull = lreg + __shfl_xor(lreg, 32, 64);
    float rl = 1.0f / lfull;
    short* orow = Xout + (size_t)(b * Sc + q0 + l31) * Dc + h * 64;
#pragma unroll
    for (int g = 0; g < 4; g++) {
        short4 o;
        o.x = f2bf(xacc0[4 * g + 0] * rl);
        o.y = f2bf(xacc0[4 * g + 1] * rl);
        o.z = f2bf(xacc0[4 * g + 2] * rl);
        o.w = f2bf(xacc0[4 * g + 3] * rl);
        *(short4*)(orow + 4 * hi + 8 * g) = o;
    }
#pragma unroll
    for (int g = 0; g < 4; g++) {
        short4 o;
        o.x = f2bf(xacc1[4 * g + 0] * rl);
        o.y = f2bf(xacc1[4 * g + 1] * rl);
        o.z = f2bf(xacc1[4 * g + 2] * rl);
        o.w = f2bf(xacc1[4 * g + 3] * rl);
        *(short4*)(orow + 32 + 4 * hi + 8 * g) = o;
    }
}

// ---------------- launch ----------------

extern "C" void kernel_launch(void* const* d_in, const int* in_sizes, int n_in,
                              void* d_out, int out_size, void* d_ws, size_t ws_size,
                              hipStream_t stream) {
    const float* batch = (const float*)d_in[0];
    const unsigned char* mask = (const unsigned char*)d_in[1];
    const float* Wq = (const float*)d_in[2];
    const float* bq = (const float*)d_in[3];
    const float* Wk = (const float*)d_in[4];
    const float* bk = (const float*)d_in[5];
    const float* Wv = (const float*)d_in[6];
    const float* bv = (const float*)d_in[7];
    const float* Wo = (const float*)d_in[8];
    const float* bo = (const float*)d_in[9];

    char* ws = (char*)d_ws;
    short* XB    = (short*)(ws + OFF_XB);
    short* WQKVT = (short*)(ws + OFF_WQKVT);
    short* WOT   = (short*)(ws + OFF_WOT);
    short* Qb    = (short*)(ws + OFF_Q);
    short* Kb    = (short*)(ws + OFF_K);
    short* VTb   = (short*)(ws + OFF_VT);
    short* XAb   = (short*)(ws + OFF_XA);
    float* BIASC = (float*)(ws + OFF_BIASC);
    int*   LENS  = (int*)(ws + OFF_LENS);
    short* Vscr  = (short*)d_out;   // V (B,H,S,64) scratch in d_out (overwritten by gemm_out)

    cast_bf16_kernel<<<4096, 256, 0, stream>>>(batch, XB, 1048576);
    wtrans_kernel<<<dim3(32, 32, 4), dim3(32, 8), 0, stream>>>(Wq, Wk, Wv, Wo, WQKVT, WOT);
    prep_small_kernel<<<3, 1024, 0, stream>>>(bq, bk, bv, mask, BIASC, LENS);

    gemm_qkv_kernel<<<dim3(32, 24), 256, 0, stream>>>(XB, WQKVT, BIASC, Qb, Kb, Vscr);
    vtrans_kernel<<<dim3(32, 32), 256, 0, stream>>>(Vscr, VTb);
    attn_kernel<<<512, 256, 0, stream>>>(Qb, Kb, VTb, LENS, XAb);
    gemm_out_kernel<<<dim3(32, 16), 256, 0, stream>>>(XAb, WOT, bo, (float*)d_out);
}

// Round 11
// 119.047 us; speedup vs baseline: 1.2623x; 1.0471x over previous
//
#include <hip/hip_runtime.h>
#include <hip/hip_bf16.h>

#define DEV __device__ __forceinline__

typedef short bf16x8 __attribute__((ext_vector_type(8)));
typedef float f32x4  __attribute__((ext_vector_type(4)));
typedef float f32x16 __attribute__((ext_vector_type(16)));

#define Bc 2
#define Sc 2048
#define Dc 1024
#define Hc 16
// DEPTH = 64, M = B*S = 4096

// ---- workspace layout (bytes) ----
#define OFF_XB    0u           // batch bf16        [4096][1024]   8388608
#define OFF_WQKVT 8388608u     // Wqkv^T bf16       [3072][1024]   6291456
#define OFF_WOT   14680064u    // Wo^T bf16         [1024][1024]   2097152
#define OFF_Q     16777216u    // Q bf16 (B,H,S,64), pre-scaled    8388608
#define OFF_K     25165824u    // K bf16 (B,H,S,64)                8388608
#define OFF_VT    33554432u    // V^T bf16 (B,H,64,S) KEY-PERMUTED 8388608
#define OFF_XA    41943040u    // attn out bf16 [4096][1024]       8388608
#define OFF_BIASC 50331648u    // f32 [3072]                         12288
#define OFF_LENS  50343936u    // int [B]
// V (B,H,S,64) bf16 scratch lives in d_out[0..8MB) — rewritten every call,
// consumed by vtrans, then fully overwritten by gemm_out (deterministic).

DEV short f2bf(float f) {
    __hip_bfloat16 h = __float2bfloat16(f);
    union { __hip_bfloat16 h; short s; } u; u.h = h; return u.s;
}

DEV int cvtpk(float lo, float hi_) {
    int r;
    asm("v_cvt_pk_bf16_f32 %0, %1, %2" : "=v"(r) : "v"(lo), "v"(hi_));
    return r;
}

DEV float vexp2(float x) {
    float r;
    asm("v_exp_f32 %0, %1" : "=v"(r) : "v"(x));   // hardware 2^x, ~1 ULP
    return r;
}

DEV void gload16(const void* g, void* l) {
    __builtin_amdgcn_global_load_lds((const __attribute__((address_space(1))) void*)g,
                                     (__attribute__((address_space(3))) void*)l, 16, 0, 0);
}

union I4BF { int i[4]; bf16x8 v; };

// V^T is stored KEY-PERMUTED at rest (vtrans): within each 16-key group, storage
// order is keys (0,1,2,3,8,9,10,11,4,5,6,7,12,13,14,15). So the A-fragment for
// mfma(V,P) — lane half hi needs keys {4hi..4hi+3, 8+4hi..8+4hi+3} — is one
// contiguous ds_read_b128 at group byte + hi*16.
DEV bf16x8 vread(const char* Vc, int row, int grp, int hi16, int rsw) {
    return *(const bf16x8*)(Vc + row * 128 + ((grp + hi16) ^ rsw));
}

// ---------------- fused prep: cast + 4x weight transpose + bias/mask ----------------
__global__ __launch_bounds__(256) void prep_all_kernel(
    const float* __restrict__ batch,
    const float* __restrict__ Wq, const float* __restrict__ Wk,
    const float* __restrict__ Wv, const float* __restrict__ Wo,
    const float* __restrict__ bq, const float* __restrict__ bk, const float* __restrict__ bv,
    const unsigned char* __restrict__ mask,
    short* __restrict__ XB, short* __restrict__ WQKVT, short* __restrict__ WOT,
    float* __restrict__ biasc, int* __restrict__ lens)
{
    __shared__ float tsm[32][33];
    __shared__ int cnt;
    int blk = blockIdx.x, t = threadIdx.x;

    if (blk < 4096) {                       // ---- cast batch f32 -> bf16 (float4/lane)
        int i = blk * 256 + t;
        float4 v = ((const float4*)batch)[i];
        short4 o;
        o.x = f2bf(v.x); o.y = f2bf(v.y); o.z = f2bf(v.z); o.w = f2bf(v.w);
        ((short4*)XB)[i] = o;
        return;
    }
    if (blk < 8192) {                       // ---- weight transpose-cast (4 x 1024 tiles)
        int w = blk - 4096, z = w >> 10, tile = w & 1023;
        const float* src; short* dst;
        if (z == 0)      { src = Wq; dst = WQKVT; }
        else if (z == 1) { src = Wk; dst = WQKVT + 1024 * 1024; }
        else if (z == 2) { src = Wv; dst = WQKVT + 2 * 1024 * 1024; }
        else             { src = Wo; dst = WOT; }
        int tx = t & 31, ty = t >> 5;       // 32 x 8
        int r0 = (tile >> 5) * 32, c0 = (tile & 31) * 32;
#pragma unroll
        for (int i = 0; i < 4; i++)
            tsm[ty + i * 8][tx] = src[(size_t)(r0 + ty + i * 8) * Dc + c0 + tx];
        __syncthreads();
#pragma unroll
        for (int i = 0; i < 4; i++)
            dst[(size_t)(c0 + ty + i * 8) * Dc + r0 + tx] = f2bf(tsm[tx][ty + i * 8]);
        return;
    }
    if (blk == 8192) {                      // ---- bias concat
        for (int i = t; i < Dc; i += 256) {
            biasc[i] = bq[i]; biasc[Dc + i] = bk[i]; biasc[2 * Dc + i] = bv[i];
        }
        return;
    }
    {                                       // ---- mask lengths (blocks 8193, 8194)
        int b = blk - 8193;
        bool is_i32 = (mask[1] == 0);
        if (t == 0) cnt = 0;
        __syncthreads();
        int local = 0;
        for (int s = t; s < Sc; s += 256) {
            bool v = is_i32 ? (((const int*)mask)[b * Sc + s] != 0) : (mask[b * Sc + s] != 0);
            local += v ? 1 : 0;
        }
        atomicAdd(&cnt, local);
        __syncthreads();
        if (t == 0) lens[b] = cnt;
    }
}

// V (B,H,S,64) -> V^T (B,H,64,S) with per-16-key permutation (0-3,8-11,4-7,12-15)
__global__ __launch_bounds__(256) void vtrans_kernel(const short* __restrict__ V,
                                                     short* __restrict__ VT) {
    __shared__ short t[64][65];
    int tid = threadIdx.x;
    int bh = blockIdx.y, s0 = blockIdx.x * 64;
    int rr = tid >> 2, c4 = (tid & 3) * 16;
    const short* vrow = V + ((size_t)bh * Sc + s0 + rr) * 64 + c4;
    *(bf16x8*)&t[rr][c4]     = *(const bf16x8*)(vrow);
    *(bf16x8*)&t[rr][c4 + 8] = *(const bf16x8*)(vrow + 8);
    __syncthreads();
    // thread owns output d=rr, one 16-key group starting at s0+c4 (16-aligned)
    bf16x8 a, b2;
#pragma unroll
    for (int i = 0; i < 4; i++) {
        a[i]      = t[c4 + i][rr];          // keys 0..3
        a[4 + i]  = t[c4 + 8 + i][rr];      // keys 8..11
        b2[i]     = t[c4 + 4 + i][rr];      // keys 4..7
        b2[4 + i] = t[c4 + 12 + i][rr];     // keys 12..15
    }
    short* orow = VT + ((size_t)bh * 64 + rr) * Sc + s0 + c4;
    *(bf16x8*)(orow)     = a;
    *(bf16x8*)(orow + 8) = b2;
}

// ---------------- 128x128 bf16 MFMA GEMM: QKV projection ----------------
__global__ __launch_bounds__(256) void gemm_qkv_kernel(
    const short* __restrict__ A, const short* __restrict__ BT, const float* __restrict__ bias,
    short* __restrict__ Qp, short* __restrict__ Kp, short* __restrict__ Vp)
{
    __shared__ short As[128 * 32];
    __shared__ short Bs[128 * 32];
    int tid = threadIdx.x, lane = tid & 63, wave = tid >> 6;
    int l15 = lane & 15, lhi = lane >> 4;
    int bm = blockIdx.x, bn = blockIdx.y;
    int wm = wave >> 1, wn = wave & 1;

    const f32x4 fzero = {0.f, 0.f, 0.f, 0.f};
    f32x4 acc[4][4];
#pragma unroll
    for (int i = 0; i < 4; i++)
#pragma unroll
        for (int j = 0; j < 4; j++) acc[i][j] = fzero;

    const char* Ab = (const char*)A;
    const char* Bb = (const char*)BT;

    for (int k0 = 0; k0 < 1024; k0 += 32) {
#pragma unroll
        for (int i = 0; i < 2; i++) {
            int o = wave * 2048 + i * 1024 + lane * 16;
            int row = o >> 6, cb = o & 63;
            gload16(Ab + ((size_t)(bm * 128 + row) * 1024 + k0) * 2 + cb,
                    (char*)As + wave * 2048 + i * 1024);
            gload16(Bb + ((size_t)(bn * 128 + row) * 1024 + k0) * 2 + cb,
                    (char*)Bs + wave * 2048 + i * 1024);
        }
        __syncthreads();
        bf16x8 af[4], bfv[4];
#pragma unroll
        for (int i = 0; i < 4; i++) {
            af[i]  = *(const bf16x8*)(As + (wm * 64 + i * 16 + l15) * 32 + lhi * 8);
            bfv[i] = *(const bf16x8*)(Bs + (wn * 64 + i * 16 + l15) * 32 + lhi * 8);
        }
#pragma unroll
        for (int i = 0; i < 4; i++)
#pragma unroll
            for (int j = 0; j < 4; j++)
                acc[i][j] = __builtin_amdgcn_mfma_f32_16x16x32_bf16(af[i], bfv[j], acc[i][j], 0, 0, 0);
        __syncthreads();
    }

#pragma unroll
    for (int i = 0; i < 4; i++)
#pragma unroll
        for (int j = 0; j < 4; j++) {
            int c = bn * 128 + wn * 64 + j * 16 + l15;
            float bc = bias[c];
            int rb = bm * 128 + wm * 64 + i * 16 + 4 * lhi;
#pragma unroll
            for (int reg = 0; reg < 4; reg++) {
                int r = rb + reg;
                float v = acc[i][j][reg] + bc;
                int which = c >> 10, cc = c & 1023, h = cc >> 6, d = cc & 63;
                int b = r >> 11, s = r & 2047;
                int bh = b * Hc + h;
                if (which == 0) v *= 0.18033688f;   // fold 1/8 * log2(e) into Q
                short sv = f2bf(v);
                size_t idx = ((size_t)bh * Sc + s) * 64 + d;
                if (which == 0)      Qp[idx] = sv;
                else if (which == 1) Kp[idx] = sv;
                else                 Vp[idx] = sv;
            }
        }
}

// ---------------- 128x64 bf16 MFMA GEMM: output projection (f32 out) ----------------
__global__ __launch_bounds__(256) void gemm_out_kernel(
    const short* __restrict__ A, const short* __restrict__ BT, const float* __restrict__ bias,
    float* __restrict__ outF)
{
    __shared__ short As[128 * 32];
    __shared__ short Bs[64 * 32];
    int tid = threadIdx.x, lane = tid & 63, wave = tid >> 6;
    int l15 = lane & 15, lhi = lane >> 4;
    int bm = blockIdx.x, bn = blockIdx.y;

    const f32x4 fzero = {0.f, 0.f, 0.f, 0.f};
    f32x4 acc[2][4];
#pragma unroll
    for (int i = 0; i < 2; i++)
#pragma unroll
        for (int j = 0; j < 4; j++) acc[i][j] = fzero;

    const char* Ab = (const char*)A;
    const char* Bb = (const char*)BT;

    for (int k0 = 0; k0 < 1024; k0 += 32) {
#pragma unroll
        for (int i = 0; i < 2; i++) {
            int o = wave * 2048 + i * 1024 + lane * 16;
            int row = o >> 6, cb = o & 63;
            gload16(Ab + ((size_t)(bm * 128 + row) * 1024 + k0) * 2 + cb,
                    (char*)As + wave * 2048 + i * 1024);
        }
        {
            int o = wave * 1024 + lane * 16;
            int row = o >> 6, cb = o & 63;
            gload16(Bb + ((size_t)(bn * 64 + row) * 1024 + k0) * 2 + cb,
                    (char*)Bs + wave * 1024);
        }
        __syncthreads();
        bf16x8 af[2], bfv[4];
#pragma unroll
        for (int i = 0; i < 2; i++)
            af[i] = *(const bf16x8*)(As + (wave * 32 + i * 16 + l15) * 32 + lhi * 8);
#pragma unroll
        for (int j = 0; j < 4; j++)
            bfv[j] = *(const bf16x8*)(Bs + (j * 16 + l15) * 32 + lhi * 8);
#pragma unroll
        for (int i = 0; i < 2; i++)
#pragma unroll
            for (int j = 0; j < 4; j++)
                acc[i][j] = __builtin_amdgcn_mfma_f32_16x16x32_bf16(af[i], bfv[j], acc[i][j], 0, 0, 0);
        __syncthreads();
    }

#pragma unroll
    for (int i = 0; i < 2; i++)
#pragma unroll
        for (int j = 0; j < 4; j++) {
            int c = bn * 64 + j * 16 + l15;
            float bc = bias[c];
            int rb = bm * 128 + wave * 32 + i * 16 + 4 * lhi;
#pragma unroll
            for (int reg = 0; reg < 4; reg++)
                outF[(size_t)(rb + reg) * Dc + c] = acc[i][j][reg] + bc;
        }
}

// ---------------- flash attention: fixed-shift softmax, permuted-V b128 PV ----------
// 2-wave blocks (64 q-rows), 1D grid 1024, batch-balanced bijective XCD swizzle
// (XCD c owns heads {2c,2c+1} of both batches). 32KB LDS -> up to 5 blocks/CU, grid
// 4/CU average -> dynamic tail rebalancing of the variable-length key loops.
__global__ __launch_bounds__(128) void attn_kernel(
    const short* __restrict__ Qp, const short* __restrict__ Kp, const short* __restrict__ VTp,
    const int* __restrict__ lens, short* __restrict__ Xout)
{
    int tid = threadIdx.x, lane = tid & 63, wave = tid >> 6;   // wave 0..1
    int l31 = lane & 31, hi = lane >> 5;

    int orig = blockIdx.x;                  // 1024 blocks, 1024 % 8 == 0 -> bijective
    int xcd = orig & 7, idx = orig >> 3;    // idx 0..127 within XCD
    int j = idx & 3, bx = idx >> 2;         // bx 0..31
    int bh = ((j >> 1) << 4) + xcd * 2 + (j & 1);
    int b = bh >> 4, h = bh & 15;
    int q0 = bx * 64 + wave * 32;

    __shared__ short Kt[2][64 * 64];
    __shared__ short Vt[2][64 * 64];

    const short* Qb  = Qp + (size_t)bh * Sc * 64;
    const char*  Kb  = (const char*)(Kp + (size_t)bh * Sc * 64);
    const char*  VTb = (const char*)(VTp + (size_t)bh * 64 * Sc);

    bf16x8 qf[4];
#pragma unroll
    for (int kk = 0; kk < 4; kk++)
        qf[kk] = *(const bf16x8*)(Qb + (size_t)(q0 + l31) * 64 + kk * 16 + hi * 8);

    f32x16 xacc0, xacc1, FZV;
#pragma unroll
    for (int r = 0; r < 16; r++) { xacc0[r] = 0.f; xacc1[r] = 0.f; FZV[r] = 0.f; }
    float lreg = 0.f;

    int len = lens[b];
    int nt = (len + 63) >> 6;
    int rsw = (l31 & 7) << 4;
    int hi16 = hi * 16;

#define STAGE(bufi, kt_)                                                              \
    {                                                                                 \
        int k0_ = (kt_) * 64;                                                         \
        _Pragma("unroll")                                                             \
        for (int i = 0; i < 4; i++) {                                                 \
            int o = wave * 1024 + i * 2048 + lane * 16;                               \
            int row = o >> 7, cb = o & 127;                                           \
            int scb = cb ^ ((row & 7) << 4);                                          \
            gload16(Kb + (size_t)(k0_ + row) * 128 + scb,                             \
                    (char*)&Kt[bufi][0] + wave * 1024 + i * 2048);                    \
            gload16(VTb + (size_t)row * (Sc * 2) + (size_t)k0_ * 2 + scb,             \
                    (char*)&Vt[bufi][0] + wave * 1024 + i * 2048);                    \
        }                                                                             \
    }

#define DOHALF(Kc, Vc, ROFF, KBASE, KT)                                               \
    {                                                                                 \
        __builtin_amdgcn_s_setprio(1);                                                \
        bf16x8 kf0 = *(const bf16x8*)((Kc) + (ROFF + l31) * 128 + (hi16 ^ rsw));      \
        f32x16 s = __builtin_amdgcn_mfma_f32_32x32x16_bf16(kf0, qf[0], FZV, 0, 0, 0); \
        _Pragma("unroll")                                                             \
        for (int kk = 1; kk < 4; kk++) {                                              \
            bf16x8 kf = *(const bf16x8*)((Kc) + (ROFF + l31) * 128 +                  \
                                         ((kk * 32 + hi16) ^ rsw));                   \
            s = __builtin_amdgcn_mfma_f32_32x32x16_bf16(kf, qf[kk], s, 0, 0, 0);      \
        }                                                                             \
        __builtin_amdgcn_s_setprio(0);                                                \
        if ((KT) == nt - 1) {                                                         \
            int rem = len - (KT) * 64;                                                \
            if (rem < (KBASE) + 32) {                                                 \
                _Pragma("unroll")                                                     \
                for (int r = 0; r < 16; r++) {                                        \
                    int key0 = (KBASE) + 4 * hi + (r & 3) + 8 * (r >> 2);             \
                    if (key0 >= rem) s[r] = -3.0e38f;                                 \
                }                                                                     \
            }                                                                         \
        }                                                                             \
        _Pragma("unroll")                                                             \
        for (int r = 0; r < 16; r++) s[r] = vexp2(s[r]);                              \
        {   /* depth-4 tree sum (breaks the 16-deep serial add chain) */              \
            float a0 = s[0] + s[1],   a1 = s[2] + s[3];                               \
            float a2 = s[4] + s[5],   a3 = s[6] + s[7];                               \
            float a4 = s[8] + s[9],   a5 = s[10] + s[11];                             \
            float a6 = s[12] + s[13], a7 = s[14] + s[15];                             \
            float b0 = a0 + a1, b1 = a2 + a3, b2 = a4 + a5, b3 = a6 + a7;             \
            lreg += (b0 + b1) + (b2 + b3);                                            \
        }                                                                             \
        I4BF u, w;                                                                    \
        u.i[0] = cvtpk(s[0], s[1]);   u.i[1] = cvtpk(s[2], s[3]);                     \
        u.i[2] = cvtpk(s[4], s[5]);   u.i[3] = cvtpk(s[6], s[7]);                     \
        w.i[0] = cvtpk(s[8], s[9]);   w.i[1] = cvtpk(s[10], s[11]);                   \
        w.i[2] = cvtpk(s[12], s[13]); w.i[3] = cvtpk(s[14], s[15]);                   \
        __builtin_amdgcn_s_setprio(1);                                                \
        {                                                                             \
            bf16x8 v0 = vread((Vc), l31,      (KBASE) * 2,      hi16, rsw);           \
            bf16x8 v1 = vread((Vc), 32 + l31, (KBASE) * 2,      hi16, rsw);           \
            xacc0 = __builtin_amdgcn_mfma_f32_32x32x16_bf16(v0, u.v, xacc0, 0, 0, 0); \
            xacc1 = __builtin_amdgcn_mfma_f32_32x32x16_bf16(v1, u.v, xacc1, 0, 0, 0); \
            bf16x8 v2 = vread((Vc), l31,      (KBASE) * 2 + 32, hi16, rsw);           \
            bf16x8 v3 = vread((Vc), 32 + l31, (KBASE) * 2 + 32, hi16, rsw);           \
            xacc0 = __builtin_amdgcn_mfma_f32_32x32x16_bf16(v2, w.v, xacc0, 0, 0, 0); \
            xacc1 = __builtin_amdgcn_mfma_f32_32x32x16_bf16(v3, w.v, xacc1, 0, 0, 0); \
        }                                                                             \
        __builtin_amdgcn_s_setprio(0);                                                \
    }

#define DOTILE(BUFI, KT)                                                              \
    {                                                                                 \
        const char* Kc_ = (const char*)&Kt[BUFI][0];                                  \
        const char* Vc_ = (const char*)&Vt[BUFI][0];                                  \
        DOHALF(Kc_, Vc_, 0, 0, KT);                                                   \
        DOHALF(Kc_, Vc_, 32, 32, KT);                                                 \
    }

    STAGE(0, 0);
    __syncthreads();

    int kt = 0;
    while (kt + 2 <= nt) {
        if (kt + 1 < nt) STAGE(1, kt + 1);
        DOTILE(0, kt);
        __syncthreads();
        if (kt + 2 < nt) STAGE(0, kt + 2);
        DOTILE(1, kt + 1);
        __syncthreads();
        kt += 2;
    }
    if (kt < nt) DOTILE(0, kt);

    // epilogue: l = sum over both lane halves; d = {0,32} + 4*hi + 8*g + (0..3)
    float lfull = lreg + __shfl_xor(lreg, 32, 64);
    float rl = 1.0f / lfull;
    short* orow = Xout + (size_t)(b * Sc + q0 + l31) * Dc + h * 64;
#pragma unroll
    for (int g = 0; g < 4; g++) {
        short4 o;
        o.x = f2bf(xacc0[4 * g + 0] * rl);
        o.y = f2bf(xacc0[4 * g + 1] * rl);
        o.z = f2bf(xacc0[4 * g + 2] * rl);
        o.w = f2bf(xacc0[4 * g + 3] * rl);
        *(short4*)(orow + 4 * hi + 8 * g) = o;
    }
#pragma unroll
    for (int g = 0; g < 4; g++) {
        short4 o;
        o.x = f2bf(xacc1[4 * g + 0] * rl);
        o.y = f2bf(xacc1[4 * g + 1] * rl);
        o.z = f2bf(xacc1[4 * g + 2] * rl);
        o.w = f2bf(xacc1[4 * g + 3] * rl);
        *(short4*)(orow + 32 + 4 * hi + 8 * g) = o;
    }
}

// ---------------- launch ----------------

extern "C" void kernel_launch(void* const* d_in, const int* in_sizes, int n_in,
                              void* d_out, int out_size, void* d_ws, size_t ws_size,
                              hipStream_t stream) {
    const float* batch = (const float*)d_in[0];
    const unsigned char* mask = (const unsigned char*)d_in[1];
    const float* Wq = (const float*)d_in[2];
    const float* bq = (const float*)d_in[3];
    const float* Wk = (const float*)d_in[4];
    const float* bk = (const float*)d_in[5];
    const float* Wv = (const float*)d_in[6];
    const float* bv = (const float*)d_in[7];
    const float* Wo = (const float*)d_in[8];
    const float* bo = (const float*)d_in[9];

    char* ws = (char*)d_ws;
    short* XB    = (short*)(ws + OFF_XB);
    short* WQKVT = (short*)(ws + OFF_WQKVT);
    short* WOT   = (short*)(ws + OFF_WOT);
    short* Qb    = (short*)(ws + OFF_Q);
    short* Kb    = (short*)(ws + OFF_K);
    short* VTb   = (short*)(ws + OFF_VT);
    short* XAb   = (short*)(ws + OFF_XA);
    float* BIASC = (float*)(ws + OFF_BIASC);
    int*   LENS  = (int*)(ws + OFF_LENS);
    short* Vscr  = (short*)d_out;   // V (B,H,S,64) scratch in d_out (overwritten by gemm_out)

    prep_all_kernel<<<8195, 256, 0, stream>>>(batch, Wq, Wk, Wv, Wo, bq, bk, bv, mask,
                                              XB, WQKVT, WOT, BIASC, LENS);
    gemm_qkv_kernel<<<dim3(32, 24), 256, 0, stream>>>(XB, WQKVT, BIASC, Qb, Kb, Vscr);
    vtrans_kernel<<<dim3(32, 32), 256, 0, stream>>>(Vscr, VTb);
    attn_kernel<<<1024, 128, 0, stream>>>(Qb, Kb, VTb, LENS, XAb);
    gemm_out_kernel<<<dim3(32, 16), 256, 0, stream>>>(XAb, WOT, bo, (float*)d_out);
}